// Round 3
// baseline (876.807 us; speedup 1.0000x reference)
//
#include <hip/hip_runtime.h>
#include <math.h>

#define Bb 128
#define Tt 1024
#define Ll 96

typedef float v2f __attribute__((ext_vector_type(2)));
typedef float v4f __attribute__((ext_vector_type(4)));

// One block = ONE wave = TWO independent batches (b, b+64), recurrences
// interleaved in the instruction stream. Rationale: a single recurrence is
// dependent-latency-bound (~37% VALU busy on its SIMD, rest stalls); the
// second batch's independent instructions fill those stall slots. E=exp(trans)
// is batch-independent -> shared register table, near-zero marginal VGPR cost.
//
// Linear-space recurrence per batch (log/exp off the serial critical path):
//   q_t = (E^T q_{t-1}) * exp(x_t) * 2^{-k_{t-1}},  E = exp(trans)
//   k_t = floor(log2 q_t[0]) via exponent bits (readfirstlane -> SALU)
//   true state_t = log q_t + D_t,  D_t += k_{t-1}*ln2  (Dk integer: EXACT)
__global__ __launch_bounds__(64, 1) void crf_fwd_kernel(
    const float* __restrict__ inputs,      // (B, T, L) fp32
    const int*   __restrict__ labels_idx,  // (B, T) int32
    const float* __restrict__ trans,       // (L, L) fp32
    float*       __restrict__ out)         // (B, 1) fp32
{
    const int bA  = blockIdx.x;            // batch A
    const int bB  = bA + (Bb / 2);         // batch B
    const int i   = threadIdx.x;                     // 0..63
    const int col = (2 * i < Ll) ? 2 * i : (Ll - 2); // clamp lanes 48..63

    __shared__ __align__(16) float bufA[2][Ll];      // double-buffered qA
    __shared__ __align__(16) float bufB[2][Ll];      // double-buffered qB

    const float* xA = inputs + (size_t)bA * Tt * Ll;
    const float* xB = inputs + (size_t)bB * Tt * Ll;

    // ---- point_score + trans_score, both batches interleaved ----
    float psA = 0.f, psB = 0.f;
    {
        const int* lA = labels_idx + bA * Tt;
        const int* lB = labels_idx + bB * Tt;
        #pragma unroll 4
        for (int t = i; t < Tt; t += 64) {
            int a0 = lA[t], b0 = lB[t];
            psA += xA[t * Ll + a0];
            psB += xB[t * Ll + b0];
            if (t < Tt - 1) {
                psA += trans[a0 * Ll + lA[t + 1]];
                psB += trans[b0 * Ll + lB[t + 1]];
            }
        }
        #pragma unroll
        for (int off = 32; off; off >>= 1) {
            psA += __shfl_xor(psA, off, 64);
            psB += __shfl_xor(psB, off, 64);
        }
    }

    // ---- E in 96 named v2f registers (shared by both batches) ----
    // EA<p> = {E[2p][col],   E[2p+1][col]}   (output m = col)
    // EB<p> = {E[2p][col+1], E[2p+1][col+1]} (output m = col+1)
    v2f EA0,EA1,EA2,EA3,EA4,EA5,EA6,EA7,EA8,EA9,EA10,EA11,EA12,EA13,EA14,EA15,
        EA16,EA17,EA18,EA19,EA20,EA21,EA22,EA23,EA24,EA25,EA26,EA27,EA28,EA29,
        EA30,EA31,EA32,EA33,EA34,EA35,EA36,EA37,EA38,EA39,EA40,EA41,EA42,EA43,
        EA44,EA45,EA46,EA47;
    v2f EB0,EB1,EB2,EB3,EB4,EB5,EB6,EB7,EB8,EB9,EB10,EB11,EB12,EB13,EB14,EB15,
        EB16,EB17,EB18,EB19,EB20,EB21,EB22,EB23,EB24,EB25,EB26,EB27,EB28,EB29,
        EB30,EB31,EB32,EB33,EB34,EB35,EB36,EB37,EB38,EB39,EB40,EB41,EB42,EB43,
        EB44,EB45,EB46,EB47;

#define EINIT(p) { \
        v2f r0 = *reinterpret_cast<const v2f*>(&trans[(2 * (p))     * Ll + col]); \
        v2f r1 = *reinterpret_cast<const v2f*>(&trans[(2 * (p) + 1) * Ll + col]); \
        EA##p = (v2f){__expf(r0.x), __expf(r1.x)}; \
        EB##p = (v2f){__expf(r0.y), __expf(r1.y)}; }
    EINIT(0)  EINIT(1)  EINIT(2)  EINIT(3)  EINIT(4)  EINIT(5)  EINIT(6)  EINIT(7)
    EINIT(8)  EINIT(9)  EINIT(10) EINIT(11) EINIT(12) EINIT(13) EINIT(14) EINIT(15)
    EINIT(16) EINIT(17) EINIT(18) EINIT(19) EINIT(20) EINIT(21) EINIT(22) EINIT(23)
    EINIT(24) EINIT(25) EINIT(26) EINIT(27) EINIT(28) EINIT(29) EINIT(30) EINIT(31)
    EINIT(32) EINIT(33) EINIT(34) EINIT(35) EINIT(36) EINIT(37) EINIT(38) EINIT(39)
    EINIT(40) EINIT(41) EINIT(42) EINIT(43) EINIT(44) EINIT(45) EINIT(46) EINIT(47)
#undef EINIT

    // ---- init both recurrences ----
    v2f x0A = *reinterpret_cast<const v2f*>(&xA[col]);
    v2f x0B = *reinterpret_cast<const v2f*>(&xB[col]);
    v2f qvA = (v2f){__expf(x0A.x), __expf(x0A.y)};
    v2f qvB = (v2f){__expf(x0B.x), __expf(x0B.y)};
    if (i < 48) {
        *reinterpret_cast<v2f*>(&bufA[0][2 * i]) = qvA;
        *reinterpret_cast<v2f*>(&bufB[0][2 * i]) = qvB;
    }
    unsigned gA = (unsigned)__builtin_amdgcn_readfirstlane((int)__float_as_uint(qvA.x));
    unsigned gB = (unsigned)__builtin_amdgcn_readfirstlane((int)__float_as_uint(qvB.x));
    int   kA = (int)((gA >> 23) & 0xffu) - 127;
    int   kB = (int)((gB >> 23) & 0xffu) - 127;
    float rA = __uint_as_float((unsigned)(127 - kA) << 23);   // exact 2^-k
    float rB = __uint_as_float((unsigned)(127 - kB) << 23);
    int   DkA = 0, DkB = 0;

    // ---- x prefetch (depth 2) + exp(x) pipelined one step ahead ----
    v2f x1A = *reinterpret_cast<const v2f*>(&xA[1 * Ll + col]);
    v2f x1B = *reinterpret_cast<const v2f*>(&xB[1 * Ll + col]);
    v2f exwA = (v2f){__expf(x1A.x), __expf(x1A.y)};
    v2f exwB = (v2f){__expf(x1B.x), __expf(x1B.y)};
    v2f xaA = *reinterpret_cast<const v2f*>(&xA[2 * Ll + col]);
    v2f xaB = *reinterpret_cast<const v2f*>(&xB[2 * Ll + col]);
    v2f xbA = *reinterpret_cast<const v2f*>(&xA[3 * Ll + col]);
    v2f xbB = *reinterpret_cast<const v2f*>(&xB[3 * Ll + col]);

    for (int t = 1; t < Tt; ++t) {
        const int wp = t & 1, rp = wp ^ 1;

        DkA += kA; DkB += kB;              // integer, exact
        v2f wA = exwA * rA;                // exp(x_t)*2^-k : off the FMA path
        v2f wB = exwB * rB;

        // ---- two independent matvecs, interleaved: 8 FMA chains ----
        const v4f* qpA = reinterpret_cast<const v4f*>(&bufA[rp][0]);
        const v4f* qpB = reinterpret_cast<const v4f*>(&bufB[rp][0]);
        v2f aA00 = {0.f,0.f}, aA01 = {0.f,0.f}, aA10 = {0.f,0.f}, aA11 = {0.f,0.f};
        v2f aB00 = {0.f,0.f}, aB01 = {0.f,0.f}, aB10 = {0.f,0.f}, aB11 = {0.f,0.f};
#define FSTEP2(J, P0, P1, P2, P3) { \
        v4f qa0 = qpA[2 * (J)];     v4f qb0 = qpB[2 * (J)]; \
        v4f qa1 = qpA[2 * (J) + 1]; v4f qb1 = qpB[2 * (J) + 1]; \
        v2f Alo = {qa0.x, qa0.y}, Ahi = {qa0.z, qa0.w}; \
        v2f Blo = {qb0.x, qb0.y}, Bhi = {qb0.z, qb0.w}; \
        v2f Alo2 = {qa1.x, qa1.y}, Ahi2 = {qa1.z, qa1.w}; \
        v2f Blo2 = {qb1.x, qb1.y}, Bhi2 = {qb1.z, qb1.w}; \
        aA00 += Alo  * EA##P0;  aB00 += Blo  * EA##P0; \
        aA10 += Alo  * EB##P0;  aB10 += Blo  * EB##P0; \
        aA01 += Ahi  * EA##P1;  aB01 += Bhi  * EA##P1; \
        aA11 += Ahi  * EB##P1;  aB11 += Bhi  * EB##P1; \
        aA00 += Alo2 * EA##P2;  aB00 += Blo2 * EA##P2; \
        aA10 += Alo2 * EB##P2;  aB10 += Blo2 * EB##P2; \
        aA01 += Ahi2 * EA##P3;  aB01 += Bhi2 * EA##P3; \
        aA11 += Ahi2 * EB##P3;  aB11 += Bhi2 * EB##P3; }
        FSTEP2(0,  0,  1,  2,  3)
        FSTEP2(1,  4,  5,  6,  7)
        FSTEP2(2,  8,  9,  10, 11)
        FSTEP2(3,  12, 13, 14, 15)
        FSTEP2(4,  16, 17, 18, 19)
        FSTEP2(5,  20, 21, 22, 23)
        FSTEP2(6,  24, 25, 26, 27)
        FSTEP2(7,  28, 29, 30, 31)
        FSTEP2(8,  32, 33, 34, 35)
        FSTEP2(9,  36, 37, 38, 39)
        FSTEP2(10, 40, 41, 42, 43)
        FSTEP2(11, 44, 45, 46, 47)
#undef FSTEP2
        v2f sA0 = aA00 + aA01, sA1 = aA10 + aA11;
        v2f sB0 = aB00 + aB01, sB1 = aB10 + aB11;
        qvA = (v2f){sA0.x + sA0.y, sA1.x + sA1.y} * wA;
        qvB = (v2f){sB0.x + sB0.y, sB1.x + sB1.y} * wB;

        if (i < 48) {
            *reinterpret_cast<v2f*>(&bufA[wp][2 * i]) = qvA;
            *reinterpret_cast<v2f*>(&bufB[wp][2 * i]) = qvB;
        }
        // same-wave DS ops are in-order; no barrier, no manual waitcnt.

        // ---- off-path bookkeeping for step t+1 ----
        gA = (unsigned)__builtin_amdgcn_readfirstlane((int)__float_as_uint(qvA.x));
        gB = (unsigned)__builtin_amdgcn_readfirstlane((int)__float_as_uint(qvB.x));
        kA = (int)((gA >> 23) & 0xffu) - 127;
        kB = (int)((gB >> 23) & 0xffu) - 127;
        rA = __uint_as_float((unsigned)(127 - kA) << 23);
        rB = __uint_as_float((unsigned)(127 - kB) << 23);

        exwA = (v2f){__expf(xaA.x), __expf(xaA.y)};
        exwB = (v2f){__expf(xaB.x), __expf(xaB.y)};
        xaA = xbA; xaB = xbB;
        int row = t + 3; if (row > Tt - 1) row = Tt - 1;
        xbA = *reinterpret_cast<const v2f*>(&xA[row * Ll + col]);
        xbB = *reinterpret_cast<const v2f*>(&xB[row * Ll + col]);
    }

    // ---- log_norm per batch; out = log_norm - scores ----
    float sA = (i < 48) ? (qvA.x + qvA.y) : 0.f;
    float sB = (i < 48) ? (qvB.x + qvB.y) : 0.f;
    #pragma unroll
    for (int off = 32; off; off >>= 1) {
        sA += __shfl_xor(sA, off, 64);
        sB += __shfl_xor(sB, off, 64);
    }
    if (i == 0) {
        double lnA = (double)DkA * 0.6931471805599453 + log((double)sA);
        double lnB = (double)DkB * 0.6931471805599453 + log((double)sB);
        out[bA] = (float)(lnA - (double)psA);
        out[bB] = (float)(lnB - (double)psB);
    }
}

extern "C" void kernel_launch(void* const* d_in, const int* in_sizes, int n_in,
                              void* d_out, int out_size, void* d_ws, size_t ws_size,
                              hipStream_t stream) {
    const float* inputs     = (const float*)d_in[0];
    const int*   labels_idx = (const int*)d_in[1];
    const float* trans      = (const float*)d_in[2];
    float*       out        = (float*)d_out;

    crf_fwd_kernel<<<dim3(Bb / 2), dim3(64), 0, stream>>>(inputs, labels_idx, trans, out);
}

// Round 4
// 653.307 us; speedup vs baseline: 1.3421x; 1.3421x over previous
//
#include <hip/hip_runtime.h>
#include <math.h>

#define Bb 128
#define Tt 1024
#define Ll 96

typedef float v2f __attribute__((ext_vector_type(2)));
typedef float v4f __attribute__((ext_vector_type(4)));

// One block = one batch = ONE wave. Lane el (=i, mirrored for i>=48) owns
// output states ce=2*el, ce+1.
//
// KEY CHANGE (round 4): E = exp(trans) is streamed from LDS, not held in a
// per-lane register array. Rounds 0-3 all showed ~90 phantom VALU instrs/step
// (VALUBusy arithmetic) + impossible VGPR counts (68..132 < array size): the
// E array sat in AGPRs with a per-FMA copy tax. LDS layout Ea[j][lane] gives
// perfect-stride conflict-free ds_read_b128 (lanes 16B apart); lanes 48-63
// read the SAME addresses as lanes 32-47 (broadcast, free) so E traffic is
// exactly 36KB/step = 288 LDS clks. FMA operands come straight from ds_read
// destination registers - nothing left for the allocator to demote.
//
// Linear-space recurrence (log/exp off the serial critical path):
//   q_t = (E^T q_{t-1}) * exp(x_t) * 2^{-k_{t-1}},  E = exp(trans)
//   k_t = floor(log2 q_t[0]) via exponent bits (readfirstlane -> SALU)
//   true state_t = log q_t + D_t,  D_t += k_{t-1}*ln2  (Dk integer: EXACT)
__global__ __launch_bounds__(64, 1) void crf_fwd_kernel(
    const float* __restrict__ inputs,      // (B, T, L) fp32
    const int*   __restrict__ labels_idx,  // (B, T) int32
    const float* __restrict__ trans,       // (L, L) fp32
    float*       __restrict__ out)         // (B, 1) fp32
{
    const int b  = blockIdx.x;
    const int i  = threadIdx.x;                 // 0..63
    const int el = (i < 48) ? i : (i - 16);     // lanes 48..63 mirror 32..47
    const int ce = 2 * el;                      // even column owned by lane

    // Ea[j][el] = {E[4j+r][ce]} r=0..3 ; Eb same for column ce+1.
    __shared__ __align__(16) v4f  Ea[24][48];   // 18 KB
    __shared__ __align__(16) v4f  Eb[24][48];   // 18 KB
    __shared__ __align__(16) float qbuf[2][Ll]; // double-buffered q

    const float* xbase = inputs + (size_t)b * Tt * Ll;

    // ---- fill E into LDS (one-time; same-wave DS ordering, no barrier) ----
    if (i < 48) {
        #pragma unroll
        for (int j = 0; j < 24; ++j) {
            v4f a, bb;
            #pragma unroll
            for (int r = 0; r < 4; ++r) {
                a[r]  = __expf(trans[(4 * j + r) * Ll + ce]);
                bb[r] = __expf(trans[(4 * j + r) * Ll + ce + 1]);
            }
            Ea[j][el] = a;
            Eb[j][el] = bb;
        }
    }

    // ---- point_score + trans_score (independent of the scan) ----
    float ps = 0.f;
    {
        const int* lb = labels_idx + b * Tt;
        #pragma unroll 4
        for (int t = i; t < Tt; t += 64) {
            int i0 = lb[t];
            ps += xbase[t * Ll + i0];
            if (t < Tt - 1) ps += trans[i0 * Ll + lb[t + 1]];
        }
        #pragma unroll
        for (int off = 32; off; off >>= 1) ps += __shfl_xor(ps, off, 64);
    }

    // ---- q_0 = exp(x_0); seed normalizer from its exponent field ----
    v2f x0 = *reinterpret_cast<const v2f*>(&xbase[ce]);
    v2f qv = (v2f){__expf(x0.x), __expf(x0.y)};
    if (i < 48) *reinterpret_cast<v2f*>(&qbuf[0][ce]) = qv;
    unsigned gb = (unsigned)__builtin_amdgcn_readfirstlane((int)__float_as_uint(qv.x));
    int   kcur = (int)((gb >> 23) & 0xffu) - 127;               // floor(log2 q[0])
    float r    = __uint_as_float((unsigned)(127 - kcur) << 23); // exact 2^-k
    int   Dk   = 0;

    // ---- x prefetch (depth 2) + exp(x) pipelined one step ahead ----
    v2f x1 = *reinterpret_cast<const v2f*>(&xbase[1 * Ll + ce]);
    v2f exw = (v2f){__expf(x1.x), __expf(x1.y)};  // exp(x_1)
    v2f xa  = *reinterpret_cast<const v2f*>(&xbase[2 * Ll + ce]);
    v2f xb  = *reinterpret_cast<const v2f*>(&xbase[3 * Ll + ce]);

    for (int t = 1; t < Tt; ++t) {
        const int wp = t & 1, rp = wp ^ 1;

        Dk += kcur;              // D_t += k_{t-1} (integer, exact)
        v2f w = exw * r;         // exp(x_t)*2^-k : off the FMA critical path

        // ---- matvec: per chunk j: 1 broadcast q-read + 2 streamed E-reads
        //      + 4 pk-FMAs, all operands direct from ds_read results ----
        const v4f* qb = reinterpret_cast<const v4f*>(&qbuf[rp][0]);
        v2f e0 = {0.f,0.f}, e1 = {0.f,0.f}, e2 = {0.f,0.f}, e3 = {0.f,0.f};
        v2f o0 = {0.f,0.f}, o1 = {0.f,0.f}, o2 = {0.f,0.f}, o3 = {0.f,0.f};
        #pragma unroll
        for (int j = 0; j < 24; j += 2) {
            v4f qc0 = qb[j];
            v4f qc1 = qb[j + 1];
            v4f ea0 = Ea[j][el];
            v4f eb0 = Eb[j][el];
            v4f ea1 = Ea[j + 1][el];
            v4f eb1 = Eb[j + 1][el];
            e0 += (v2f){qc0.x, qc0.y} * (v2f){ea0.x, ea0.y};
            e1 += (v2f){qc0.z, qc0.w} * (v2f){ea0.z, ea0.w};
            o0 += (v2f){qc0.x, qc0.y} * (v2f){eb0.x, eb0.y};
            o1 += (v2f){qc0.z, qc0.w} * (v2f){eb0.z, eb0.w};
            e2 += (v2f){qc1.x, qc1.y} * (v2f){ea1.x, ea1.y};
            e3 += (v2f){qc1.z, qc1.w} * (v2f){ea1.z, ea1.w};
            o2 += (v2f){qc1.x, qc1.y} * (v2f){eb1.x, eb1.y};
            o3 += (v2f){qc1.z, qc1.w} * (v2f){eb1.z, eb1.w};
        }
        v2f se = (e0 + e1) + (e2 + e3);
        v2f so = (o0 + o1) + (o2 + o3);
        qv = (v2f){se.x + se.y, so.x + so.y} * w;

        if (i < 48) *reinterpret_cast<v2f*>(&qbuf[wp][ce]) = qv;
        // same-wave DS ops are in-order; no barrier, no manual waitcnt.

        // ---- off-path bookkeeping for step t+1 (SALU + 2 transcendentals) ----
        gb   = (unsigned)__builtin_amdgcn_readfirstlane((int)__float_as_uint(qv.x));
        kcur = (int)((gb >> 23) & 0xffu) - 127;
        r    = __uint_as_float((unsigned)(127 - kcur) << 23);

        exw = (v2f){__expf(xa.x), __expf(xa.y)};    // exp(x_{t+1})
        xa  = xb;
        int row = t + 3; if (row > Tt - 1) row = Tt - 1;
        xb  = *reinterpret_cast<const v2f*>(&xbase[row * Ll + ce]);
    }

    // ---- log_norm = Dk*ln2 + log(sum_m q_T[m]); out = log_norm - scores ----
    float s = (i < 48) ? (qv.x + qv.y) : 0.f;
    #pragma unroll
    for (int off = 32; off; off >>= 1) s += __shfl_xor(s, off, 64);
    if (i == 0) {
        double ln = (double)Dk * 0.6931471805599453 + log((double)s);
        out[b] = (float)(ln - (double)ps);
    }
}

extern "C" void kernel_launch(void* const* d_in, const int* in_sizes, int n_in,
                              void* d_out, int out_size, void* d_ws, size_t ws_size,
                              hipStream_t stream) {
    const float* inputs     = (const float*)d_in[0];
    const int*   labels_idx = (const int*)d_in[1];
    const float* trans      = (const float*)d_in[2];
    float*       out        = (float*)d_out;

    crf_fwd_kernel<<<dim3(Bb), dim3(64), 0, stream>>>(inputs, labels_idx, trans, out);
}

// Round 5
// 611.869 us; speedup vs baseline: 1.4330x; 1.0677x over previous
//
#include <hip/hip_runtime.h>
#include <math.h>

#define Bb 128
#define Tt 1024
#define Ll 96

typedef float v2f __attribute__((ext_vector_type(2)));
typedef float v4f __attribute__((ext_vector_type(4)));

// One block = one batch = ONE wave. Lane i owns output states ce=2i, ce+1
// (clamped for i>=48; their results are never stored).
//
// Round-5 change: E = exp(trans) columns live in 176 NAMED SCALAR floats
// (rows 0..87), PINNED to arch VGPRs via empty asm "+v" constraints at loop
// top (rounds 0-2 showed the allocator demotes large E arrays to AGPRs at
// VGPR_Count ~116 and pays per-use copies; round 4 showed streaming all of E
// from LDS makes the LDS pipe the wall: 72 b128 reads ~ 864 cy/step).
// Rows 88..95 stream from a small LDS table (register-budget safety valve).
// Per-step LDS: 24 q-broadcast reads + 4 streamed-E reads + 1 write.
//
// Linear-space recurrence (log/exp off the serial critical path):
//   q_t = (E^T q_{t-1}) * exp(x_t) * 2^{-k_{t-1}},  E = exp(trans)
//   k_t = floor(log2 q_t[0]) via exponent bits (readfirstlane -> SALU)
//   true state_t = log q_t + D_t,  D_t += k_{t-1}*ln2  (Dk integer: EXACT)
__global__ __launch_bounds__(64, 1) void crf_fwd_kernel(
    const float* __restrict__ inputs,      // (B, T, L) fp32
    const int*   __restrict__ labels_idx,  // (B, T) int32
    const float* __restrict__ trans,       // (L, L) fp32
    float*       __restrict__ out)         // (B, 1) fp32
{
    const int b   = blockIdx.x;
    const int i   = threadIdx.x;                     // 0..63
    const int col = (2 * i < Ll) ? 2 * i : (Ll - 2); // clamp lanes 48..63
    const int el  = (i < 48) ? i : 47;               // streamed-E lane slot

    __shared__ __align__(16) float qbuf[2][Ll];      // double-buffered q
    __shared__ __align__(16) v4f Sa0[48], Sb0[48];   // E rows 88..91 (cols ce/ce+1)
    __shared__ __align__(16) v4f Sa1[48], Sb1[48];   // E rows 92..95

    const float* xbase = inputs + (size_t)b * Tt * Ll;

    // ---- point_score + trans_score (before E goes live: short live ranges) ----
    float ps = 0.f;
    {
        const int* lb = labels_idx + b * Tt;
        #pragma unroll 4
        for (int t = i; t < Tt; t += 64) {
            int i0 = lb[t];
            ps += xbase[t * Ll + i0];
            if (t < Tt - 1) ps += trans[i0 * Ll + lb[t + 1]];
        }
        #pragma unroll
        for (int off = 32; off; off >>= 1) ps += __shfl_xor(ps, off, 64);
    }

    // ---- streamed-E LDS table (rows 88..95) ----
    if (i < 48) {
        v4f a0, b0, a1, b1;
        #pragma unroll
        for (int r = 0; r < 4; ++r) {
            a0[r] = __expf(trans[(88 + r) * Ll + col]);
            b0[r] = __expf(trans[(88 + r) * Ll + col + 1]);
            a1[r] = __expf(trans[(92 + r) * Ll + col]);
            b1[r] = __expf(trans[(92 + r) * Ll + col + 1]);
        }
        Sa0[i] = a0; Sb0[i] = b0; Sa1[i] = a1; Sb1[i] = b1;
    }

    // ---- E rows 0..87 in 176 named scalar floats ----
#define EROWS(X) \
    X(0)  X(1)  X(2)  X(3)  X(4)  X(5)  X(6)  X(7)  X(8)  X(9)  X(10) X(11) \
    X(12) X(13) X(14) X(15) X(16) X(17) X(18) X(19) X(20) X(21) X(22) X(23) \
    X(24) X(25) X(26) X(27) X(28) X(29) X(30) X(31) X(32) X(33) X(34) X(35) \
    X(36) X(37) X(38) X(39) X(40) X(41) X(42) X(43) X(44) X(45) X(46) X(47) \
    X(48) X(49) X(50) X(51) X(52) X(53) X(54) X(55) X(56) X(57) X(58) X(59) \
    X(60) X(61) X(62) X(63) X(64) X(65) X(66) X(67) X(68) X(69) X(70) X(71) \
    X(72) X(73) X(74) X(75) X(76) X(77) X(78) X(79) X(80) X(81) X(82) X(83) \
    X(84) X(85) X(86) X(87)

#define EDECL(n) float EA##n, EB##n;
    EROWS(EDECL)
#undef EDECL

#define EINIT(n) { v2f r_ = *reinterpret_cast<const v2f*>(&trans[(n) * Ll + col]); \
                   EA##n = __expf(r_.x); EB##n = __expf(r_.y); }
    EROWS(EINIT)
#undef EINIT

    // VGPR pin: empty asm, "+v" ties each E value to an arch VGPR (no code).
#define PR(n) "+v"(EA##n), "+v"(EB##n)
#define PIN_ALL \
    asm("" : PR(0),  PR(1),  PR(2),  PR(3),  PR(4),  PR(5));  \
    asm("" : PR(6),  PR(7),  PR(8),  PR(9),  PR(10), PR(11)); \
    asm("" : PR(12), PR(13), PR(14), PR(15), PR(16), PR(17)); \
    asm("" : PR(18), PR(19), PR(20), PR(21), PR(22), PR(23)); \
    asm("" : PR(24), PR(25), PR(26), PR(27), PR(28), PR(29)); \
    asm("" : PR(30), PR(31), PR(32), PR(33), PR(34), PR(35)); \
    asm("" : PR(36), PR(37), PR(38), PR(39), PR(40), PR(41)); \
    asm("" : PR(42), PR(43), PR(44), PR(45), PR(46), PR(47)); \
    asm("" : PR(48), PR(49), PR(50), PR(51), PR(52), PR(53)); \
    asm("" : PR(54), PR(55), PR(56), PR(57), PR(58), PR(59)); \
    asm("" : PR(60), PR(61), PR(62), PR(63), PR(64), PR(65)); \
    asm("" : PR(66), PR(67), PR(68), PR(69), PR(70), PR(71)); \
    asm("" : PR(72), PR(73), PR(74), PR(75), PR(76), PR(77)); \
    asm("" : PR(78), PR(79), PR(80), PR(81), PR(82), PR(83)); \
    asm("" : PR(84), PR(85), PR(86), PR(87));
    PIN_ALL

    // ---- q_0 = exp(x_0); seed normalizer from its exponent field ----
    v2f x0 = *reinterpret_cast<const v2f*>(&xbase[col]);
    float qx = __expf(x0.x), qy = __expf(x0.y);
    if (i < 48) *reinterpret_cast<v2f*>(&qbuf[0][col]) = (v2f){qx, qy};
    unsigned gb = (unsigned)__builtin_amdgcn_readfirstlane((int)__float_as_uint(qx));
    int   kcur = (int)((gb >> 23) & 0xffu) - 127;               // floor(log2 q[0])
    float r    = __uint_as_float((unsigned)(127 - kcur) << 23); // exact 2^-k
    int   Dk   = 0;

    // ---- x prefetch (depth 2) + exp(x) pipelined one step ahead ----
    v2f x1  = *reinterpret_cast<const v2f*>(&xbase[1 * Ll + col]);
    float ewx = __expf(x1.x), ewy = __expf(x1.y);   // exp(x_1)
    v2f xa  = *reinterpret_cast<const v2f*>(&xbase[2 * Ll + col]);
    v2f xb  = *reinterpret_cast<const v2f*>(&xbase[3 * Ll + col]);

    #pragma unroll 1
    for (int t = 1; t < Tt; ++t) {
        const int wp = t & 1, rp = wp ^ 1;

        PIN_ALL                      // keep E in arch VGPRs through the loop

        Dk += kcur;                  // D_t += k_{t-1} (integer, exact)
        float wx = ewx * r;          // exp(x_t)*2^-k : off the FMA critical path
        float wy = ewy * r;

        // streamed-E reads: issue early, data needed only for chunks 22/23
        v4f sa0 = Sa0[el], sb0 = Sb0[el], sa1 = Sa1[el], sb1 = Sb1[el];

        // ---- matvec: 22 register-E chunks + 2 streamed chunks ----
        const v4f* qb = reinterpret_cast<const v4f*>(&qbuf[rp][0]);
        float a0 = 0.f, a1 = 0.f, a2 = 0.f, a3 = 0.f;
        float b0 = 0.f, b1 = 0.f, b2 = 0.f, b3 = 0.f;
#define CH(c, n0, n1, n2, n3) { v4f qc = qb[c]; \
        a0 += qc.x * EA##n0;  b0 += qc.x * EB##n0; \
        a1 += qc.y * EA##n1;  b1 += qc.y * EB##n1; \
        a2 += qc.z * EA##n2;  b2 += qc.z * EB##n2; \
        a3 += qc.w * EA##n3;  b3 += qc.w * EB##n3; }
        CH(0,  0,  1,  2,  3)   CH(1,  4,  5,  6,  7)
        CH(2,  8,  9,  10, 11)  CH(3,  12, 13, 14, 15)
        CH(4,  16, 17, 18, 19)  CH(5,  20, 21, 22, 23)
        CH(6,  24, 25, 26, 27)  CH(7,  28, 29, 30, 31)
        CH(8,  32, 33, 34, 35)  CH(9,  36, 37, 38, 39)
        CH(10, 40, 41, 42, 43)  CH(11, 44, 45, 46, 47)
        CH(12, 48, 49, 50, 51)  CH(13, 52, 53, 54, 55)
        CH(14, 56, 57, 58, 59)  CH(15, 60, 61, 62, 63)
        CH(16, 64, 65, 66, 67)  CH(17, 68, 69, 70, 71)
        CH(18, 72, 73, 74, 75)  CH(19, 76, 77, 78, 79)
        CH(20, 80, 81, 82, 83)  CH(21, 84, 85, 86, 87)
#undef CH
        {   // chunk 22: rows 88..91 (streamed)
            v4f qc = qb[22];
            a0 += qc.x * sa0.x;  b0 += qc.x * sb0.x;
            a1 += qc.y * sa0.y;  b1 += qc.y * sb0.y;
            a2 += qc.z * sa0.z;  b2 += qc.z * sb0.z;
            a3 += qc.w * sa0.w;  b3 += qc.w * sb0.w;
        }
        {   // chunk 23: rows 92..95 (streamed)
            v4f qc = qb[23];
            a0 += qc.x * sa1.x;  b0 += qc.x * sb1.x;
            a1 += qc.y * sa1.y;  b1 += qc.y * sb1.y;
            a2 += qc.z * sa1.z;  b2 += qc.z * sb1.z;
            a3 += qc.w * sa1.w;  b3 += qc.w * sb1.w;
        }
        qx = ((a0 + a1) + (a2 + a3)) * wx;
        qy = ((b0 + b1) + (b2 + b3)) * wy;

        if (i < 48) *reinterpret_cast<v2f*>(&qbuf[wp][col]) = (v2f){qx, qy};
        // same-wave DS ops are in-order; no barrier, no manual waitcnt.

        // ---- off-path bookkeeping for step t+1 ----
        gb   = (unsigned)__builtin_amdgcn_readfirstlane((int)__float_as_uint(qx));
        kcur = (int)((gb >> 23) & 0xffu) - 127;
        r    = __uint_as_float((unsigned)(127 - kcur) << 23);

        ewx = __expf(xa.x); ewy = __expf(xa.y);     // exp(x_{t+1})
        xa  = xb;
        int row = t + 3; if (row > Tt - 1) row = Tt - 1;
        xb  = *reinterpret_cast<const v2f*>(&xbase[row * Ll + col]);
    }
#undef PR
#undef PIN_ALL
#undef EROWS

    // ---- log_norm = Dk*ln2 + log(sum_m q_T[m]); out = log_norm - scores ----
    float s = (i < 48) ? (qx + qy) : 0.f;
    #pragma unroll
    for (int off = 32; off; off >>= 1) s += __shfl_xor(s, off, 64);
    if (i == 0) {
        double ln = (double)Dk * 0.6931471805599453 + log((double)s);
        out[b] = (float)(ln - (double)ps);
    }
}

extern "C" void kernel_launch(void* const* d_in, const int* in_sizes, int n_in,
                              void* d_out, int out_size, void* d_ws, size_t ws_size,
                              hipStream_t stream) {
    const float* inputs     = (const float*)d_in[0];
    const int*   labels_idx = (const int*)d_in[1];
    const float* trans      = (const float*)d_in[2];
    float*       out        = (float*)d_out;

    crf_fwd_kernel<<<dim3(Bb), dim3(64), 0, stream>>>(inputs, labels_idx, trans, out);
}

// Round 6
// 575.628 us; speedup vs baseline: 1.5232x; 1.0630x over previous
//
#include <hip/hip_runtime.h>
#include <math.h>

#define Bb 128
#define Tt 1024
#define Ll 96

typedef float v2f __attribute__((ext_vector_type(2)));

// One block = one batch = ONE wave. Lane i owns output states col=2i, col+1
// (clamped for i>=48; their q values are garbage and never read back).
//
// Round-6 structure (from the round-3 decomposition: step = work 665cy +
// serial bubble 590cy that never overlaps):
//  * q is WAVE-UNIFORM per element -> distribute via v_readlane into SGPRs
//    (96/step) and FMA as v_fmac_f32 acc, s_q, v_E. NO LDS in the loop at
//    all: the ds_write->ds_read turnaround and the LDS pipe are gone.
//  * x prefetch depth 6 (named regs): ~6 iterations ≈ >1800 cy in flight
//    covers the ~900 cy HBM-miss latency that was the per-step vmcnt bubble.
//  * E init is FENCED per row (asm memory clobber) so the 96 trans loads
//    cannot cluster: peak pressure stays ~200 regs, giving the allocator a
//    chance to keep E's live range in arch VGPRs instead of AGPRs (rounds
//    0-5 all paid a per-FMA AGPR-copy tax from init-time pressure spikes).
//
// Linear-space recurrence (log/exp off the serial critical path):
//   q_t = (E^T q_{t-1}) * exp(x_t) * 2^{-k_{t-1}},  E = exp(trans)
//   k_t = floor(log2 q_t[0]) via exponent bits (readfirstlane -> SALU)
//   true state_t = log q_t + D_t,  D_t += k_{t-1}*ln2  (Dk integer: EXACT)
__global__ __launch_bounds__(64, 1)
__attribute__((amdgpu_waves_per_eu(1)))
void crf_fwd_kernel(
    const float* __restrict__ inputs,      // (B, T, L) fp32
    const int*   __restrict__ labels_idx,  // (B, T) int32
    const float* __restrict__ trans,       // (L, L) fp32
    float*       __restrict__ out)         // (B, 1) fp32
{
    const int b   = blockIdx.x;
    const int i   = threadIdx.x;                     // 0..63
    const int col = (2 * i < Ll) ? 2 * i : (Ll - 2); // clamp lanes 48..63

    const float* xbase = inputs + (size_t)b * Tt * Ll;

    // ---- point_score + trans_score (before E goes live) ----
    float ps = 0.f;
    {
        const int* lb = labels_idx + b * Tt;
        #pragma unroll 4
        for (int t = i; t < Tt; t += 64) {
            int i0 = lb[t];
            ps += xbase[t * Ll + i0];
            if (t < Tt - 1) ps += trans[i0 * Ll + lb[t + 1]];
        }
        #pragma unroll
        for (int off = 32; off; off >>= 1) ps += __shfl_xor(ps, off, 64);
    }

    // ---- E rows 0..95 in 192 named scalar floats, fenced sequential init ----
#define EROWS(X) \
    X(0)  X(1)  X(2)  X(3)  X(4)  X(5)  X(6)  X(7)  X(8)  X(9)  X(10) X(11) \
    X(12) X(13) X(14) X(15) X(16) X(17) X(18) X(19) X(20) X(21) X(22) X(23) \
    X(24) X(25) X(26) X(27) X(28) X(29) X(30) X(31) X(32) X(33) X(34) X(35) \
    X(36) X(37) X(38) X(39) X(40) X(41) X(42) X(43) X(44) X(45) X(46) X(47) \
    X(48) X(49) X(50) X(51) X(52) X(53) X(54) X(55) X(56) X(57) X(58) X(59) \
    X(60) X(61) X(62) X(63) X(64) X(65) X(66) X(67) X(68) X(69) X(70) X(71) \
    X(72) X(73) X(74) X(75) X(76) X(77) X(78) X(79) X(80) X(81) X(82) X(83) \
    X(84) X(85) X(86) X(87) X(88) X(89) X(90) X(91) X(92) X(93) X(94) X(95)

#define EDECL(n) float EA##n, EB##n;
    EROWS(EDECL)
#undef EDECL

    // Fence after every row: forbids clustering all 96 loads (the pressure
    // spike that forced E into AGPRs in rounds 0-5).
#define EINIT(n) { v2f r_ = *reinterpret_cast<const v2f*>(&trans[(n) * Ll + col]); \
                   EA##n = __expf(r_.x); EB##n = __expf(r_.y); \
                   asm volatile("" ::: "memory"); }
    EROWS(EINIT)
#undef EINIT
#undef EROWS

    // ---- q_0 = exp(x_0); seed normalizer from its exponent field ----
    v2f x0 = *reinterpret_cast<const v2f*>(&xbase[col]);
    float qx = __expf(x0.x), qy = __expf(x0.y);
    int   gb = __builtin_amdgcn_readfirstlane(__float_as_int(qx));
    int   kcur = ((gb >> 23) & 0xff) - 127;                     // floor(log2 q[0])
    float r    = __uint_as_float((unsigned)(127 - kcur) << 23); // exact 2^-k
    int   Dk   = 0;

    // ---- x queue: ewx/ewy = exp(row t); x2..x7 = rows t+1..t+6 ----
    v2f x1 = *reinterpret_cast<const v2f*>(&xbase[1 * Ll + col]);
    float ewx = __expf(x1.x), ewy = __expf(x1.y);
    v2f x2 = *reinterpret_cast<const v2f*>(&xbase[2 * Ll + col]);
    v2f x3 = *reinterpret_cast<const v2f*>(&xbase[3 * Ll + col]);
    v2f x4 = *reinterpret_cast<const v2f*>(&xbase[4 * Ll + col]);
    v2f x5 = *reinterpret_cast<const v2f*>(&xbase[5 * Ll + col]);
    v2f x6 = *reinterpret_cast<const v2f*>(&xbase[6 * Ll + col]);
    v2f x7 = *reinterpret_cast<const v2f*>(&xbase[7 * Ll + col]);

    #pragma unroll 1
    for (int t = 1; t < Tt; ++t) {
        Dk += kcur;                  // D_t += k_{t-1} (integer, exact)
        float wx = ewx * r;          // exp(x_t)*2^-k
        float wy = ewy * r;

        // ---- matvec: per 4 rows, 4 readlanes (q -> SGPR) + 8 scalar FMAs ----
        const int qxb = __float_as_int(qx);
        const int qyb = __float_as_int(qy);
        float a0 = 0.f, a1 = 0.f, a2 = 0.f, a3 = 0.f;
        float b0 = 0.f, b1 = 0.f, b2 = 0.f, b3 = 0.f;
#define CH(j, n0, n1, n2, n3) { \
        float f0 = __int_as_float(__builtin_amdgcn_readlane(qxb, 2*(j)));     \
        float f1 = __int_as_float(__builtin_amdgcn_readlane(qyb, 2*(j)));     \
        float f2 = __int_as_float(__builtin_amdgcn_readlane(qxb, 2*(j) + 1)); \
        float f3 = __int_as_float(__builtin_amdgcn_readlane(qyb, 2*(j) + 1)); \
        a0 += f0 * EA##n0;  b0 += f0 * EB##n0; \
        a1 += f1 * EA##n1;  b1 += f1 * EB##n1; \
        a2 += f2 * EA##n2;  b2 += f2 * EB##n2; \
        a3 += f3 * EA##n3;  b3 += f3 * EB##n3; }
        CH(0,  0,  1,  2,  3)   CH(1,  4,  5,  6,  7)
        CH(2,  8,  9,  10, 11)  CH(3,  12, 13, 14, 15)
        CH(4,  16, 17, 18, 19)  CH(5,  20, 21, 22, 23)
        CH(6,  24, 25, 26, 27)  CH(7,  28, 29, 30, 31)
        CH(8,  32, 33, 34, 35)  CH(9,  36, 37, 38, 39)
        CH(10, 40, 41, 42, 43)  CH(11, 44, 45, 46, 47)
        CH(12, 48, 49, 50, 51)  CH(13, 52, 53, 54, 55)
        CH(14, 56, 57, 58, 59)  CH(15, 60, 61, 62, 63)
        CH(16, 64, 65, 66, 67)  CH(17, 68, 69, 70, 71)
        CH(18, 72, 73, 74, 75)  CH(19, 76, 77, 78, 79)
        CH(20, 80, 81, 82, 83)  CH(21, 84, 85, 86, 87)
        CH(22, 88, 89, 90, 91)  CH(23, 92, 93, 94, 95)
#undef CH
        qx = ((a0 + a1) + (a2 + a3)) * wx;
        qy = ((b0 + b1) + (b2 + b3)) * wy;

        // ---- off-path bookkeeping for step t+1 ----
        gb   = __builtin_amdgcn_readfirstlane(__float_as_int(qx));
        kcur = ((gb >> 23) & 0xff) - 127;
        r    = __uint_as_float((unsigned)(127 - kcur) << 23);

        ewx = __expf(x2.x); ewy = __expf(x2.y);     // exp(x_{t+1})
        x2 = x3; x3 = x4; x4 = x5; x5 = x6; x6 = x7;
        int row = t + 7; if (row > Tt - 1) row = Tt - 1;
        x7 = *reinterpret_cast<const v2f*>(&xbase[row * Ll + col]);
    }

    // ---- log_norm = Dk*ln2 + log(sum_m q_T[m]); out = log_norm - scores ----
    float s = (i < 48) ? (qx + qy) : 0.f;
    #pragma unroll
    for (int off = 32; off; off >>= 1) s += __shfl_xor(s, off, 64);
    if (i == 0) {
        double ln = (double)Dk * 0.6931471805599453 + log((double)s);
        out[b] = (float)(ln - (double)ps);
    }
}

extern "C" void kernel_launch(void* const* d_in, const int* in_sizes, int n_in,
                              void* d_out, int out_size, void* d_ws, size_t ws_size,
                              hipStream_t stream) {
    const float* inputs     = (const float*)d_in[0];
    const int*   labels_idx = (const int*)d_in[1];
    const float* trans      = (const float*)d_in[2];
    float*       out        = (float*)d_out;

    crf_fwd_kernel<<<dim3(Bb), dim3(64), 0, stream>>>(inputs, labels_idx, trans, out);
}

// Round 7
// 331.548 us; speedup vs baseline: 2.6446x; 1.7362x over previous
//
#include <hip/hip_runtime.h>
#include <math.h>

#define Bb 128
#define Tt 1024
#define Ll 96

typedef float v2f __attribute__((ext_vector_type(2)));

// One block = one batch = TWO waves running INDEPENDENT halves of the chain:
//   wave 0 (forward):  q_t = (E^T q_{t-1}) o w_t,  t = 1..511
//   wave 1 (backward): v_{t-1} = E (v_t o w_t),    t = 1023..512, v_1023 = 1
// Meeting point: log_norm = log(v_511 . q_511) + (Dk_f + Dk_b)*ln2.
// The recurrence is LINEAR (q_t = diag(w_t) E^T q_{t-1}), so evaluating
// 1^T M_1023..M_1 q_0 from both ends halves the serial chain: 1023 -> 512
// steps. Per-step machinery is round 6's verbatim (readlane q-distribution,
// zero LDS in loop, depth-6 x-prefetch, exponent-field rescale; Dk integer).
// Waves touch LDS only at the final exchange (one barrier total).
__global__ __launch_bounds__(128, 1)
__attribute__((amdgpu_waves_per_eu(1)))
void crf_fwd_kernel(
    const float* __restrict__ inputs,      // (B, T, L) fp32
    const int*   __restrict__ labels_idx,  // (B, T) int32
    const float* __restrict__ trans,       // (L, L) fp32
    float*       __restrict__ out)         // (B, 1) fp32
{
    const int b    = blockIdx.x;
    const int tid  = threadIdx.x;                    // 0..127
    const int wave = tid >> 6;
    const int i    = tid & 63;                       // lane
    const int col  = (2 * i < Ll) ? 2 * i : (Ll - 2); // clamp lanes 48..63

    __shared__ __align__(16) float qex[Ll];   // forward q_511
    __shared__ __align__(16) float uex[Ll];   // backward v_511
    __shared__ float wps[2];                  // per-wave score partials
    __shared__ int   dks[2];                  // per-wave Dk

    const float* xbase = inputs + (size_t)b * Tt * Ll;

    // ---- point_score + trans_score, split across both waves ----
    float ps = 0.f;
    {
        const int* lb = labels_idx + b * Tt;
        #pragma unroll 4
        for (int t = tid; t < Tt; t += 128) {
            int i0 = lb[t];
            ps += xbase[t * Ll + i0];
            if (t < Tt - 1) ps += trans[i0 * Ll + lb[t + 1]];
        }
        #pragma unroll
        for (int off = 32; off; off >>= 1) ps += __shfl_xor(ps, off, 64);
        if (i == 0) wps[wave] = ps;
    }

#define EROWS(X) \
    X(0)  X(1)  X(2)  X(3)  X(4)  X(5)  X(6)  X(7)  X(8)  X(9)  X(10) X(11) \
    X(12) X(13) X(14) X(15) X(16) X(17) X(18) X(19) X(20) X(21) X(22) X(23) \
    X(24) X(25) X(26) X(27) X(28) X(29) X(30) X(31) X(32) X(33) X(34) X(35) \
    X(36) X(37) X(38) X(39) X(40) X(41) X(42) X(43) X(44) X(45) X(46) X(47) \
    X(48) X(49) X(50) X(51) X(52) X(53) X(54) X(55) X(56) X(57) X(58) X(59) \
    X(60) X(61) X(62) X(63) X(64) X(65) X(66) X(67) X(68) X(69) X(70) X(71) \
    X(72) X(73) X(74) X(75) X(76) X(77) X(78) X(79) X(80) X(81) X(82) X(83) \
    X(84) X(85) X(86) X(87) X(88) X(89) X(90) X(91) X(92) X(93) X(94) X(95)

// matvec chunk: distribute 4 wave-uniform values via readlane, 8 FMAs.
#define CH(j, n0, n1, n2, n3) { \
        float f0 = __int_as_float(__builtin_amdgcn_readlane(sxb, 2*(j)));     \
        float f1 = __int_as_float(__builtin_amdgcn_readlane(syb, 2*(j)));     \
        float f2 = __int_as_float(__builtin_amdgcn_readlane(sxb, 2*(j) + 1)); \
        float f3 = __int_as_float(__builtin_amdgcn_readlane(syb, 2*(j) + 1)); \
        a0 += f0 * EA##n0;  b0 += f0 * EB##n0; \
        a1 += f1 * EA##n1;  b1 += f1 * EB##n1; \
        a2 += f2 * EA##n2;  b2 += f2 * EB##n2; \
        a3 += f3 * EA##n3;  b3 += f3 * EB##n3; }
#define CHALL \
        CH(0,  0,  1,  2,  3)   CH(1,  4,  5,  6,  7)  \
        CH(2,  8,  9,  10, 11)  CH(3,  12, 13, 14, 15) \
        CH(4,  16, 17, 18, 19)  CH(5,  20, 21, 22, 23) \
        CH(6,  24, 25, 26, 27)  CH(7,  28, 29, 30, 31) \
        CH(8,  32, 33, 34, 35)  CH(9,  36, 37, 38, 39) \
        CH(10, 40, 41, 42, 43)  CH(11, 44, 45, 46, 47) \
        CH(12, 48, 49, 50, 51)  CH(13, 52, 53, 54, 55) \
        CH(14, 56, 57, 58, 59)  CH(15, 60, 61, 62, 63) \
        CH(16, 64, 65, 66, 67)  CH(17, 68, 69, 70, 71) \
        CH(18, 72, 73, 74, 75)  CH(19, 76, 77, 78, 79) \
        CH(20, 80, 81, 82, 83)  CH(21, 84, 85, 86, 87) \
        CH(22, 88, 89, 90, 91)  CH(23, 92, 93, 94, 95)

    float qx, qy;          // this wave's two owned state elements
    int   Dk = 0;

    if (wave == 0) {
        // ================= FORWARD: t = 1..511 =================
#define EDECL(n) float EA##n, EB##n;
        EROWS(EDECL)
#undef EDECL
        // column layout: EA_n = E[n][col], EB_n = E[n][col+1]
#define EINIT(n) { v2f r_ = *reinterpret_cast<const v2f*>(&trans[(n) * Ll + col]); \
                   EA##n = __expf(r_.x); EB##n = __expf(r_.y); \
                   asm volatile("" ::: "memory"); }
        EROWS(EINIT)
#undef EINIT

        v2f x0 = *reinterpret_cast<const v2f*>(&xbase[col]);
        qx = __expf(x0.x); qy = __expf(x0.y);
        int gb = __builtin_amdgcn_readfirstlane(__float_as_int(qx));
        int   kcur = ((gb >> 23) & 0xff) - 127;
        float r    = __uint_as_float((unsigned)(127 - kcur) << 23);

        v2f x1 = *reinterpret_cast<const v2f*>(&xbase[1 * Ll + col]);
        float ewx = __expf(x1.x), ewy = __expf(x1.y);
        v2f x2 = *reinterpret_cast<const v2f*>(&xbase[2 * Ll + col]);
        v2f x3 = *reinterpret_cast<const v2f*>(&xbase[3 * Ll + col]);
        v2f x4 = *reinterpret_cast<const v2f*>(&xbase[4 * Ll + col]);
        v2f x5 = *reinterpret_cast<const v2f*>(&xbase[5 * Ll + col]);
        v2f x6 = *reinterpret_cast<const v2f*>(&xbase[6 * Ll + col]);
        v2f x7 = *reinterpret_cast<const v2f*>(&xbase[7 * Ll + col]);

        #pragma unroll 1
        for (int t = 1; t <= Tt / 2 - 1; ++t) {
            Dk += kcur;
            float wx = ewx * r;
            float wy = ewy * r;

            const int sxb = __float_as_int(qx);
            const int syb = __float_as_int(qy);
            float a0 = 0.f, a1 = 0.f, a2 = 0.f, a3 = 0.f;
            float b0 = 0.f, b1 = 0.f, b2 = 0.f, b3 = 0.f;
            CHALL
            qx = ((a0 + a1) + (a2 + a3)) * wx;
            qy = ((b0 + b1) + (b2 + b3)) * wy;

            gb   = __builtin_amdgcn_readfirstlane(__float_as_int(qx));
            kcur = ((gb >> 23) & 0xff) - 127;
            r    = __uint_as_float((unsigned)(127 - kcur) << 23);

            ewx = __expf(x2.x); ewy = __expf(x2.y);
            x2 = x3; x3 = x4; x4 = x5; x5 = x6; x6 = x7;
            int row = t + 7; if (row > Tt - 1) row = Tt - 1;
            x7 = *reinterpret_cast<const v2f*>(&xbase[row * Ll + col]);
        }
        if (i < 48) { qex[col] = qx; qex[col + 1] = qy; }
        if (i == 0) dks[0] = Dk;
    } else {
        // ================= BACKWARD: t = 1023..512 =================
        // v_{t-1} = E (v_t o w_t); row layout: EA_n = E[col][n], EB_n = E[col+1][n]
#define EDECL(n) float EA##n, EB##n;
        EROWS(EDECL)
#undef EDECL
#define EINIT(n) { EA##n = __expf(trans[col * Ll + (n)]); \
                   EB##n = __expf(trans[(col + 1) * Ll + (n)]); \
                   asm volatile("" ::: "memory"); }
        EROWS(EINIT)
#undef EINIT

        qx = 1.f; qy = 1.f;                    // v_1023 = 1
        int   kcur = 0;
        float r    = 1.f;

        v2f x1 = *reinterpret_cast<const v2f*>(&xbase[(Tt - 1) * Ll + col]);
        float ewx = __expf(x1.x), ewy = __expf(x1.y);
        v2f x2 = *reinterpret_cast<const v2f*>(&xbase[(Tt - 2) * Ll + col]);
        v2f x3 = *reinterpret_cast<const v2f*>(&xbase[(Tt - 3) * Ll + col]);
        v2f x4 = *reinterpret_cast<const v2f*>(&xbase[(Tt - 4) * Ll + col]);
        v2f x5 = *reinterpret_cast<const v2f*>(&xbase[(Tt - 5) * Ll + col]);
        v2f x6 = *reinterpret_cast<const v2f*>(&xbase[(Tt - 6) * Ll + col]);
        v2f x7 = *reinterpret_cast<const v2f*>(&xbase[(Tt - 7) * Ll + col]);

        #pragma unroll 1
        for (int t = Tt - 1; t >= Tt / 2; --t) {
            Dk += kcur;
            // pre-multiply: s = v o (exp(x_t) * 2^-k)
            float sx = qx * (ewx * r);
            float sy = qy * (ewy * r);

            const int sxb = __float_as_int(sx);
            const int syb = __float_as_int(sy);
            float a0 = 0.f, a1 = 0.f, a2 = 0.f, a3 = 0.f;
            float b0 = 0.f, b1 = 0.f, b2 = 0.f, b3 = 0.f;
            CHALL
            qx = (a0 + a1) + (a2 + a3);
            qy = (b0 + b1) + (b2 + b3);

            int gb = __builtin_amdgcn_readfirstlane(__float_as_int(qx));
            kcur = ((gb >> 23) & 0xff) - 127;
            r    = __uint_as_float((unsigned)(127 - kcur) << 23);

            ewx = __expf(x2.x); ewy = __expf(x2.y);
            x2 = x3; x3 = x4; x4 = x5; x5 = x6; x6 = x7;
            int row = t - 7; if (row < 0) row = 0;
            x7 = *reinterpret_cast<const v2f*>(&xbase[row * Ll + col]);
        }
        if (i < 48) { uex[col] = qx; uex[col + 1] = qy; }
        if (i == 0) dks[1] = Dk;
    }
#undef CHALL
#undef CH
#undef EROWS

    __syncthreads();

    // ---- meeting point: log_norm = log(v_511 . q_511) + (Dk_f+Dk_b)*ln2 ----
    if (wave == 0) {
        float d = (i < 48) ? (qx * uex[col] + qy * uex[col + 1]) : 0.f;
        #pragma unroll
        for (int off = 32; off; off >>= 1) d += __shfl_xor(d, off, 64);
        if (i == 0) {
            double ln = (double)(dks[0] + dks[1]) * 0.6931471805599453
                      + log((double)d);
            out[b] = (float)(ln - (double)(wps[0] + wps[1]));
        }
    }
}

extern "C" void kernel_launch(void* const* d_in, const int* in_sizes, int n_in,
                              void* d_out, int out_size, void* d_ws, size_t ws_size,
                              hipStream_t stream) {
    const float* inputs     = (const float*)d_in[0];
    const int*   labels_idx = (const int*)d_in[1];
    const float* trans      = (const float*)d_in[2];
    float*       out        = (float*)d_out;

    crf_fwd_kernel<<<dim3(Bb), dim3(128), 0, stream>>>(inputs, labels_idx, trans, out);
}